// Round 4
// baseline (120.715 us; speedup 1.0000x reference)
//
#include <hip/hip_runtime.h>
#include <cstdint>
#include <cstddef>

typedef __bf16 bf16;
typedef __bf16 bf16x8 __attribute__((ext_vector_type(8)));
typedef __bf16 bf16x4 __attribute__((ext_vector_type(4)));
typedef float  f32x4  __attribute__((ext_vector_type(4)));
typedef float  f32x16 __attribute__((ext_vector_type(16)));

constexpr int Bb  = 2;
constexpr int Ss  = 2048;
constexpr int Hh  = 768;
constexpr int NHh = 12;
constexpr int DHh = 64;
constexpr int Mm  = Bb * Ss;   // 4096
constexpr int N3  = 3 * Hh;    // 2304
constexpr int QKW = 2 * Hh;    // 1536 (Q,K packed buffer row width)

__device__ __forceinline__ float fexp2(float x) { return __builtin_amdgcn_exp2f(x); }

__device__ __forceinline__ void gload_lds16(void* lds, const void* g) {
  __builtin_amdgcn_global_load_lds(
      (__attribute__((address_space(1))) void*)(uintptr_t)g,
      (__attribute__((address_space(3))) void*)(uint32_t)(uintptr_t)lds,
      16, 0, 0);
}

__global__ void cvt_f32_bf16(const float* __restrict__ in, bf16* __restrict__ out, int n4) {
  int i = blockIdx.x * blockDim.x + threadIdx.x;
  int st = gridDim.x * blockDim.x;
  for (; i < n4; i += st) {
    float4 v = ((const float4*)in)[i];
    bf16x4 o;
    o[0] = (bf16)v.x; o[1] = (bf16)v.y; o[2] = (bf16)v.z; o[3] = (bf16)v.w;
    ((bf16x4*)out)[i] = o;
  }
}

// C = A[M,768] * Bw[N,768]^T. OUTMODE 0: bf16 out (Q,K region -> Cb stride CSTRIDE,
// V region -> VtG transposed [b][h][d][S]). OUTMODE 1: f32 out + bias, stride CSTRIDE.
template<int CSTRIDE, int OUTMODE>
__global__ __launch_bounds__(256, 2)
void gemm_bt(const bf16* __restrict__ A, const bf16* __restrict__ Bw,
             bf16* __restrict__ Cb, bf16* __restrict__ VtG,
             float* __restrict__ Cf, const float* __restrict__ bias)
{
  constexpr int K = 768;
  __shared__ bf16 As[128 * 32];
  __shared__ bf16 Bs[128 * 32];
  const int tid  = threadIdx.x;
  const int wid  = tid >> 6, lane = tid & 63;
  const int lr   = lane & 15, lk = lane >> 4;
  const int n0   = blockIdx.x * 128, m0 = blockIdx.y * 128;
  const int wm   = (wid >> 1) * 64, wn = (wid & 1) * 64;

  f32x4 acc[4][4] = {};

  const char* Ag = (const char*)(A  + (size_t)m0 * K) + (size_t)(tid >> 2) * (K * 2) + (tid & 3) * 16;
  const char* Bg = (const char*)(Bw + (size_t)n0 * K) + (size_t)(tid >> 2) * (K * 2) + (tid & 3) * 16;
  char* AsW = (char*)As + wid * 1024;
  char* BsW = (char*)Bs + wid * 1024;
  constexpr size_t rstep = (size_t)64 * K * 2;

  for (int kb = 0; kb < K; kb += 32) {
    gload_lds16(AsW,        Ag + (size_t)kb * 2);
    gload_lds16(AsW + 4096, Ag + rstep + (size_t)kb * 2);
    gload_lds16(BsW,        Bg + (size_t)kb * 2);
    gload_lds16(BsW + 4096, Bg + rstep + (size_t)kb * 2);
    __syncthreads();
    bf16x8 af[4], bfv[4];
#pragma unroll
    for (int i = 0; i < 4; ++i) {
      af[i]  = *(const bf16x8*)((const char*)As + ((wm + i * 16 + lr) * 32 + lk * 8) * 2);
      bfv[i] = *(const bf16x8*)((const char*)Bs + ((wn + i * 16 + lr) * 32 + lk * 8) * 2);
    }
#pragma unroll
    for (int i = 0; i < 4; ++i)
#pragma unroll
      for (int j = 0; j < 4; ++j)
        acc[i][j] = __builtin_amdgcn_mfma_f32_16x16x32_bf16(af[i], bfv[j], acc[i][j], 0, 0, 0);
    __syncthreads();
  }

  if constexpr (OUTMODE == 1) {
#pragma unroll
    for (int i = 0; i < 4; ++i)
#pragma unroll
      for (int j = 0; j < 4; ++j) {
        const int n = n0 + wn + j * 16 + lr;
        const float bv = bias[n];
#pragma unroll
        for (int r = 0; r < 4; ++r) {
          const int m = m0 + wm + i * 16 + lk * 4 + r;
          Cf[(size_t)m * CSTRIDE + n] = acc[i][j][r] + bv;
        }
      }
  } else {
    if (n0 < QKW) {
#pragma unroll
      for (int i = 0; i < 4; ++i)
#pragma unroll
        for (int j = 0; j < 4; ++j) {
          const int n = n0 + wn + j * 16 + lr;
#pragma unroll
          for (int r = 0; r < 4; ++r) {
            const int m = m0 + wm + i * 16 + lk * 4 + r;
            Cb[(size_t)m * CSTRIDE + n] = (bf16)acc[i][j][r];
          }
        }
    } else {
      const int bidx = m0 >> 11;
      const int s0 = (m0 & 2047) + wm + lk * 4;
#pragma unroll
      for (int i = 0; i < 4; ++i)
#pragma unroll
        for (int j = 0; j < 4; ++j) {
          const int colv = (n0 - QKW) + wn + j * 16 + lr;
          const int hh = colv >> 6, dd = colv & 63;
          bf16x4 pv;
#pragma unroll
          for (int r = 0; r < 4; ++r) pv[r] = (bf16)acc[i][j][r];
          *(bf16x4*)(VtG + (((size_t)(bidx * NHh + hh) * DHh + dd) << 11) + s0 + i * 16) = pv;
        }
    }
  }
}

// Flash attention v3: grid (32 qblocks, 24 b*h), 256 threads.
// 4 waves = 2 q-halves x 2 kv-halves. 32x32x16 MFMA, swapped QK^T (S^T).
// UNNORMALIZED softmax: P = exp2(s) (no max tracking -- |s| <~ 10, f32 headroom
// is ~2^118; softmax computed exactly as exp2(s)/sum). l via ones-MFMA.
// P^T redistribution via v_permlane32_swap_b32. V direct from L2 (VtG [d][s]).
// K double-buffered in LDS, 1 barrier/iter. kv-halves merged by summation.
__global__ __launch_bounds__(256, 3)
void attn_fwd3(const bf16* __restrict__ qk, const bf16* __restrict__ VtG,
               bf16* __restrict__ aout)
{
  __shared__ __align__(16) char lds[32768];  // K tiles: grp*16384 + buf*8192
  const int tid  = threadIdx.x;
  const int wid  = tid >> 6, lane = tid & 63;
  const int lq   = lane & 31, hi = lane >> 5;
  const int qh   = wid & 1, grp = wid >> 1;
  const int bh   = blockIdx.y;
  const int b    = bh / NHh, h = bh % NHh;
  const int q0   = blockIdx.x * 64 + qh * 32;
  const int kvbase = grp * 1024;

  // Q B-fragments, pre-scaled by SCALE*log2(e) (softmax in base-2 domain)
  constexpr float Cs = 0.18033688011112042f;  // 0.125 * log2(e)
  const bf16* qrow = qk + (size_t)(b * Ss + q0 + lq) * QKW + h * DHh;
  bf16x8 qf[4];
#pragma unroll
  for (int j = 0; j < 4; ++j) {
    bf16x8 t = *(const bf16x8*)(qrow + j * 16 + hi * 8);
#pragma unroll
    for (int e = 0; e < 8; ++e) t[e] = (bf16)((float)t[e] * Cs);
    qf[j] = t;
  }

  // K staging: linear LDS dest, global source column pre-swizzled (rule #21)
  const int strow = qh * 32 + (lane >> 3);
  const int stcol = ((lane & 7) * 16) ^ (((lane >> 3) & 7) << 4);
  const char* Kg0 = (const char*)(qk + (size_t)(b * Ss) * QKW + Hh + h * DHh)
                    + (size_t)strow * (QKW * 2) + stcol;
  auto stageK = [&](int buf, int kvt) {
    char* db = lds + grp * 16384 + buf * 8192 + qh * 4096;
    const char* sg = Kg0 + (size_t)kvt * (QKW * 2);
#pragma unroll
    for (int c = 0; c < 4; ++c)
      gload_lds16(db + c * 1024, sg + (size_t)(c * 8) * (QKW * 2));
  };

  const bf16* Vbase = VtG + (size_t)bh * DHh * Ss;  // [d][s]

  f32x16 oacc[2] = {};
  f32x16 lacc = {};
  bf16x8 ones;
#pragma unroll
  for (int e = 0; e < 8; ++e) ones[e] = (bf16)1.0f;

  stageK(0, kvbase);
  __syncthreads();

  for (int i = 0; i < 16; ++i) {
    const int cur = i & 1;
    const int kv0 = kvbase + i * 64;

    // V^T A-fragments direct from global (L2-hit); complete under softmax
    bf16x8 vf[4][2];
#pragma unroll
    for (int s = 0; s < 4; ++s)
#pragma unroll
      for (int dc = 0; dc < 2; ++dc)
        vf[s][dc] = *(const bf16x8*)(Vbase + (size_t)(dc * 32 + lq) * Ss + kv0 + s * 16 + hi * 8);

    // prefetch next K tile
    if (i < 15) stageK(cur ^ 1, kvbase + (i + 1) * 64);

    // S^T = K * Q^T  (D[kv][q]; lane: q = lq, kv = (r&3)+8*(r>>2)+4*hi +32*kvc)
    f32x16 sacc[2];
    __builtin_amdgcn_s_setprio(1);
#pragma unroll
    for (int kvc = 0; kvc < 2; ++kvc) {
      f32x16 s = {};
      const int row = kvc * 32 + lq;
      const char* kb = lds + grp * 16384 + cur * 8192 + row * 128;
      const int sw = (lq & 7) << 4;
#pragma unroll
      for (int j = 0; j < 4; ++j) {
        bf16x8 kf = *(const bf16x8*)(kb + ((j * 32 + hi * 16) ^ sw));
        s = __builtin_amdgcn_mfma_f32_32x32x16_bf16(kf, qf[j], s, 0, 0, 0);
      }
      sacc[kvc] = s;
    }
    __builtin_amdgcn_s_setprio(0);

    // P = exp2(S) unnormalized; pack to bf16 pairs
    uint32_t w[2][8];
#pragma unroll
    for (int kvc = 0; kvc < 2; ++kvc)
#pragma unroll
      for (int m = 0; m < 8; ++m) {
        union { bf16 hh[2]; uint32_t u; } cv;
        cv.hh[0] = (bf16)fexp2(sacc[kvc][2 * m]);
        cv.hh[1] = (bf16)fexp2(sacc[kvc][2 * m + 1]);
        w[kvc][m] = cv.u;
      }

    // drain K(next) stage + V loads (vmcnt0) and sync
    __syncthreads();

    // build P^T B-fragments via permlane32_swap and accumulate O^T, l
    __builtin_amdgcn_s_setprio(1);
#pragma unroll
    for (int s = 0; s < 4; ++s) {
      const int kvc = s >> 1, sb = s & 1;
      uint32_t a0 = w[kvc][4 * sb + 0], b0 = w[kvc][4 * sb + 2];
      uint32_t a1 = w[kvc][4 * sb + 1], b1 = w[kvc][4 * sb + 3];
      // swap a.hi32lanes <-> b.lo32lanes: a' = [a.lo | b.lo], b' = [a.hi | b.hi]
      asm("v_permlane32_swap_b32 %0, %1" : "+v"(a0), "+v"(b0));
      asm("v_permlane32_swap_b32 %0, %1" : "+v"(a1), "+v"(b1));
      union { uint32_t u[4]; bf16x8 v; } pf;
      pf.u[0] = a0; pf.u[1] = a1; pf.u[2] = b0; pf.u[3] = b1;
      // O^T += V^T * P^T   (D[d][q]; lane: q = lq, d = (r&3)+8*(r>>2)+4*hi +32*dc)
#pragma unroll
      for (int dc = 0; dc < 2; ++dc)
        oacc[dc] = __builtin_amdgcn_mfma_f32_32x32x16_bf16(vf[s][dc], pf.v, oacc[dc], 0, 0, 0);
      // l[q] = sum_kv P^T[kv][q]  (all D rows identical)
      lacc = __builtin_amdgcn_mfma_f32_32x32x16_bf16(ones, pf.v, lacc, 0, 0, 0);
    }
    __builtin_amdgcn_s_setprio(0);
  }

  // merge kv-halves by summation: grp1 exports (O, l) via LDS, grp0 combines
  if (grp == 1) {
    char* mb = lds + qh * 8704;
#pragma unroll
    for (int dc = 0; dc < 2; ++dc)
#pragma unroll
      for (int rr = 0; rr < 4; ++rr) {
        f32x4 t;
#pragma unroll
        for (int e = 0; e < 4; ++e) t[e] = oacc[dc][rr * 4 + e];
        *(f32x4*)(mb + (dc * 4 + rr) * 1024 + lane * 16) = t;
      }
    *(float*)(mb + 8192 + lane * 4) = lacc[0];
  }
  __syncthreads();
  if (grp == 0) {
    const char* mb = lds + qh * 8704;
    const float l2 = *(const float*)(mb + 8192 + lane * 4);
    const float linv = 1.0f / (lacc[0] + l2);
    bf16* orow = aout + (size_t)(b * Ss + q0 + lq) * Hh + h * DHh;
#pragma unroll
    for (int dc = 0; dc < 2; ++dc)
#pragma unroll
      for (int rr = 0; rr < 4; ++rr) {
        const f32x4 o2 = *(const f32x4*)(mb + (dc * 4 + rr) * 1024 + lane * 16);
        bf16x4 ov;
#pragma unroll
        for (int e = 0; e < 4; ++e)
          ov[e] = (bf16)((oacc[dc][rr * 4 + e] + o2[e]) * linv);
        *(bf16x4*)(orow + dc * 32 + rr * 8 + hi * 4) = ov;
      }
  }
}

extern "C" void kernel_launch(void* const* d_in, const int* in_sizes, int n_in,
                              void* d_out, int out_size, void* d_ws, size_t ws_size,
                              hipStream_t stream) {
  const float* x     = (const float*)d_in[0];
  const float* w_qkv = (const float*)d_in[1];
  const float* w_out = (const float*)d_in[2];
  const float* b_out = (const float*)d_in[3];
  char* ws = (char*)d_ws;
  bf16* xb    = (bf16*)(ws + 0);
  bf16* wqkvb = (bf16*)(ws + 6291456);
  bf16* woutb = (bf16*)(ws + 9830400);
  bf16* qkb   = (bf16*)(ws + 11010048);
  bf16* VtG   = (bf16*)(ws + 23592960);
  bf16* aoutb = (bf16*)(ws + 29884416);

  cvt_f32_bf16<<<3072, 256, 0, stream>>>(x,     xb,    Mm * Hh / 4);
  cvt_f32_bf16<<<1728, 256, 0, stream>>>(w_qkv, wqkvb, N3 * Hh / 4);
  cvt_f32_bf16<<<576,  256, 0, stream>>>(w_out, woutb, Hh * Hh / 4);

  gemm_bt<QKW, 0><<<dim3(18, 32), 256, 0, stream>>>(xb, wqkvb, qkb, VtG, nullptr, nullptr);
  attn_fwd3<<<dim3(32, 24), 256, 0, stream>>>(qkb, VtG, aoutb);
  gemm_bt<Hh, 1><<<dim3(6, 32), 256, 0, stream>>>(aoutb, woutb, nullptr, nullptr,
                                                  (float*)d_out, b_out);
}

// Round 5
// 120.452 us; speedup vs baseline: 1.0022x; 1.0022x over previous
//
#include <hip/hip_runtime.h>
#include <cstdint>
#include <cstddef>

typedef __bf16 bf16;
typedef __bf16 bf16x8 __attribute__((ext_vector_type(8)));
typedef __bf16 bf16x4 __attribute__((ext_vector_type(4)));
typedef float  f32x4  __attribute__((ext_vector_type(4)));
typedef float  f32x16 __attribute__((ext_vector_type(16)));

constexpr int Bb  = 2;
constexpr int Ss  = 2048;
constexpr int Hh  = 768;
constexpr int NHh = 12;
constexpr int DHh = 64;
constexpr int Mm  = Bb * Ss;   // 4096
constexpr int N3  = 3 * Hh;    // 2304
constexpr int QKW = 2 * Hh;    // 1536 (Q,K packed buffer row width)

__device__ __forceinline__ float fexp2(float x) { return __builtin_amdgcn_exp2f(x); }

__device__ __forceinline__ void gload_lds16(void* lds, const void* g) {
  __builtin_amdgcn_global_load_lds(
      (__attribute__((address_space(1))) void*)(uintptr_t)g,
      (__attribute__((address_space(3))) void*)(uint32_t)(uintptr_t)lds,
      16, 0, 0);
}

__global__ void cvt_f32_bf16(const float* __restrict__ in, bf16* __restrict__ out, int n4) {
  int i = blockIdx.x * blockDim.x + threadIdx.x;
  int st = gridDim.x * blockDim.x;
  for (; i < n4; i += st) {
    float4 v = ((const float4*)in)[i];
    bf16x4 o;
    o[0] = (bf16)v.x; o[1] = (bf16)v.y; o[2] = (bf16)v.z; o[3] = (bf16)v.w;
    ((bf16x4*)out)[i] = o;
  }
}

// C = A[M,768] * Bw[N,768]^T. OUTMODE 0: bf16 out (Q,K region -> Cb stride CSTRIDE,
// V region -> VtG transposed [b][h][d][S]). OUTMODE 1: f32 out + bias, stride CSTRIDE.
template<int CSTRIDE, int OUTMODE>
__global__ __launch_bounds__(256, 2)
void gemm_bt(const bf16* __restrict__ A, const bf16* __restrict__ Bw,
             bf16* __restrict__ Cb, bf16* __restrict__ VtG,
             float* __restrict__ Cf, const float* __restrict__ bias)
{
  constexpr int K = 768;
  __shared__ bf16 As[128 * 32];
  __shared__ bf16 Bs[128 * 32];
  const int tid  = threadIdx.x;
  const int wid  = tid >> 6, lane = tid & 63;
  const int lr   = lane & 15, lk = lane >> 4;
  const int n0   = blockIdx.x * 128, m0 = blockIdx.y * 128;
  const int wm   = (wid >> 1) * 64, wn = (wid & 1) * 64;

  f32x4 acc[4][4] = {};

  const char* Ag = (const char*)(A  + (size_t)m0 * K) + (size_t)(tid >> 2) * (K * 2) + (tid & 3) * 16;
  const char* Bg = (const char*)(Bw + (size_t)n0 * K) + (size_t)(tid >> 2) * (K * 2) + (tid & 3) * 16;
  char* AsW = (char*)As + wid * 1024;
  char* BsW = (char*)Bs + wid * 1024;
  constexpr size_t rstep = (size_t)64 * K * 2;

  for (int kb = 0; kb < K; kb += 32) {
    gload_lds16(AsW,        Ag + (size_t)kb * 2);
    gload_lds16(AsW + 4096, Ag + rstep + (size_t)kb * 2);
    gload_lds16(BsW,        Bg + (size_t)kb * 2);
    gload_lds16(BsW + 4096, Bg + rstep + (size_t)kb * 2);
    __syncthreads();
    bf16x8 af[4], bfv[4];
#pragma unroll
    for (int i = 0; i < 4; ++i) {
      af[i]  = *(const bf16x8*)((const char*)As + ((wm + i * 16 + lr) * 32 + lk * 8) * 2);
      bfv[i] = *(const bf16x8*)((const char*)Bs + ((wn + i * 16 + lr) * 32 + lk * 8) * 2);
    }
#pragma unroll
    for (int i = 0; i < 4; ++i)
#pragma unroll
      for (int j = 0; j < 4; ++j)
        acc[i][j] = __builtin_amdgcn_mfma_f32_16x16x32_bf16(af[i], bfv[j], acc[i][j], 0, 0, 0);
    __syncthreads();
  }

  if constexpr (OUTMODE == 1) {
#pragma unroll
    for (int i = 0; i < 4; ++i)
#pragma unroll
      for (int j = 0; j < 4; ++j) {
        const int n = n0 + wn + j * 16 + lr;
        const float bv = bias[n];
#pragma unroll
        for (int r = 0; r < 4; ++r) {
          const int m = m0 + wm + i * 16 + lk * 4 + r;
          Cf[(size_t)m * CSTRIDE + n] = acc[i][j][r] + bv;
        }
      }
  } else {
    if (n0 < QKW) {
#pragma unroll
      for (int i = 0; i < 4; ++i)
#pragma unroll
        for (int j = 0; j < 4; ++j) {
          const int n = n0 + wn + j * 16 + lr;
#pragma unroll
          for (int r = 0; r < 4; ++r) {
            const int m = m0 + wm + i * 16 + lk * 4 + r;
            Cb[(size_t)m * CSTRIDE + n] = (bf16)acc[i][j][r];
          }
        }
    } else {
      const int bidx = m0 >> 11;
      const int s0 = (m0 & 2047) + wm + lk * 4;
#pragma unroll
      for (int i = 0; i < 4; ++i)
#pragma unroll
        for (int j = 0; j < 4; ++j) {
          const int colv = (n0 - QKW) + wn + j * 16 + lr;
          const int hh = colv >> 6, dd = colv & 63;
          bf16x4 pv;
#pragma unroll
          for (int r = 0; r < 4; ++r) pv[r] = (bf16)acc[i][j][r];
          *(bf16x4*)(VtG + (((size_t)(bidx * NHh + hh) * DHh + dd) << 11) + s0 + i * 16) = pv;
        }
    }
  }
}

// Flash attention v4: grid 768 blocks (flattened, XCD-swizzled head-major), 256 thr.
// 4 waves = 2 q-halves x 2 kv-halves. 32x32x16 MFMA, swapped QK^T.
// Unnormalized softmax (P = exp2(s)), l via ones-MFMA, permlane32_swap P^T.
// Counted-vmcnt schedule: barrier at iter top; V loads then K-prefetch issued;
// vmcnt(4) before PV (V ready, prefetch in flight); vmcnt(0) at iter end.
__global__ __launch_bounds__(256, 3)
void attn_fwd4(const bf16* __restrict__ qk, const bf16* __restrict__ VtG,
               bf16* __restrict__ aout)
{
  __shared__ __align__(16) char lds[32768];  // K tiles: grp*16384 + buf*8192
  const int tid  = threadIdx.x;
  const int wid  = tid >> 6, lane = tid & 63;
  const int lq   = lane & 31, hi = lane >> 5;
  const int qh   = wid & 1, grp = wid >> 1;

  // XCD swizzle (T1): 768 blocks, 8 XCDs, 96/XCD; head-major so each XCD
  // owns 3 heads -> per-XCD K/Q/V working set ~2.3MB, L2-resident.
  const int orig = blockIdx.x;
  const int swz  = (orig & 7) * 96 + (orig >> 3);
  const int qb   = swz & 31;
  const int bh   = swz >> 5;
  const int b    = bh / NHh, h = bh % NHh;
  const int q0   = qb * 64 + qh * 32;
  const int kvbase = grp * 1024;

  // Q B-fragments, pre-scaled by SCALE*log2(e) (softmax in base-2 domain)
  constexpr float Cs = 0.18033688011112042f;  // 0.125 * log2(e)
  const bf16* qrow = qk + (size_t)(b * Ss + q0 + lq) * QKW + h * DHh;
  bf16x8 qf[4];
#pragma unroll
  for (int j = 0; j < 4; ++j) {
    bf16x8 t = *(const bf16x8*)(qrow + j * 16 + hi * 8);
#pragma unroll
    for (int e = 0; e < 8; ++e) t[e] = (bf16)((float)t[e] * Cs);
    qf[j] = t;
  }

  // K staging: linear LDS dest, global source column pre-swizzled (rule #21)
  const int strow = qh * 32 + (lane >> 3);
  const int stcol = ((lane & 7) * 16) ^ (((lane >> 3) & 7) << 4);
  const char* Kg0 = (const char*)(qk + (size_t)(b * Ss) * QKW + Hh + h * DHh)
                    + (size_t)strow * (QKW * 2) + stcol;
  auto stageK = [&](int buf, int kvt) {
    char* db = lds + grp * 16384 + buf * 8192 + qh * 4096;
    const char* sg = Kg0 + (size_t)kvt * (QKW * 2);
#pragma unroll
    for (int c = 0; c < 4; ++c)
      gload_lds16(db + c * 1024, sg + (size_t)(c * 8) * (QKW * 2));
  };

  const bf16* Vbase = VtG + (size_t)bh * DHh * Ss;  // [d][s]

  f32x16 oacc[2] = {};
  f32x16 lacc = {};
  bf16x8 ones;
#pragma unroll
  for (int e = 0; e < 8; ++e) ones[e] = (bf16)1.0f;

  stageK(0, kvbase);
  asm volatile("s_waitcnt vmcnt(0)" ::: "memory");
  __builtin_amdgcn_sched_barrier(0);

#pragma unroll 1
  for (int i = 0; i < 16; ++i) {
    const int cur = i & 1;
    const int kv0 = kvbase + i * 64;

    __builtin_amdgcn_s_barrier();   // K_i (both qh halves) visible

    // V_i A-fragments from global first (oldest in vmcnt order)
    bf16x8 vf[4][2];
#pragma unroll
    for (int s = 0; s < 4; ++s)
#pragma unroll
      for (int dc = 0; dc < 2; ++dc)
        vf[s][dc] = *(const bf16x8*)(Vbase + (size_t)(dc * 32 + lq) * Ss + kv0 + s * 16 + hi * 8);

    // prefetch K_{i+1} (dummy wrap on last iter; drained before merge)
    stageK(cur ^ 1, kvbase + ((i + 1) & 15) * 64);
    __builtin_amdgcn_sched_barrier(0);

    // S^T = K * Q^T  (D[kv][q]; lane: q = lq, kv = (r&3)+8*(r>>2)+4*hi +32*kvc)
    f32x16 sacc[2];
    __builtin_amdgcn_s_setprio(1);
#pragma unroll
    for (int kvc = 0; kvc < 2; ++kvc) {
      f32x16 s = {};
      const int row = kvc * 32 + lq;
      const char* kb = lds + grp * 16384 + cur * 8192 + row * 128;
      const int sw = (lq & 7) << 4;
#pragma unroll
      for (int j = 0; j < 4; ++j) {
        bf16x8 kf = *(const bf16x8*)(kb + ((j * 32 + hi * 16) ^ sw));
        s = __builtin_amdgcn_mfma_f32_32x32x16_bf16(kf, qf[j], s, 0, 0, 0);
      }
      sacc[kvc] = s;
    }
    __builtin_amdgcn_s_setprio(0);

    // P = exp2(S) unnormalized; pack to bf16 pairs
    uint32_t w[2][8];
#pragma unroll
    for (int kvc = 0; kvc < 2; ++kvc)
#pragma unroll
      for (int m = 0; m < 8; ++m) {
        union { bf16 hh[2]; uint32_t u; } cv;
        cv.hh[0] = (bf16)fexp2(sacc[kvc][2 * m]);
        cv.hh[1] = (bf16)fexp2(sacc[kvc][2 * m + 1]);
        w[kvc][m] = cv.u;
      }

    // V_i retired (8 oldest); K-prefetch (4 newest) may stay in flight
    asm volatile("s_waitcnt vmcnt(4)" ::: "memory");
    __builtin_amdgcn_sched_barrier(0);

    // build P^T B-fragments via permlane32_swap and accumulate O^T, l
    __builtin_amdgcn_s_setprio(1);
#pragma unroll
    for (int s = 0; s < 4; ++s) {
      const int kvc = s >> 1, sb = s & 1;
      uint32_t a0 = w[kvc][4 * sb + 0], b0 = w[kvc][4 * sb + 2];
      uint32_t a1 = w[kvc][4 * sb + 1], b1 = w[kvc][4 * sb + 3];
      asm("v_permlane32_swap_b32 %0, %1" : "+v"(a0), "+v"(b0));
      asm("v_permlane32_swap_b32 %0, %1" : "+v"(a1), "+v"(b1));
      union { uint32_t u[4]; bf16x8 v; } pf;
      pf.u[0] = a0; pf.u[1] = a1; pf.u[2] = b0; pf.u[3] = b1;
#pragma unroll
      for (int dc = 0; dc < 2; ++dc)
        oacc[dc] = __builtin_amdgcn_mfma_f32_32x32x16_bf16(vf[s][dc], pf.v, oacc[dc], 0, 0, 0);
      lacc = __builtin_amdgcn_mfma_f32_32x32x16_bf16(ones, pf.v, lacc, 0, 0, 0);
    }
    __builtin_amdgcn_s_setprio(0);

    // my K-prefetch landed (full-iteration window); barrier at next iter top
    asm volatile("s_waitcnt vmcnt(0)" ::: "memory");
    __builtin_amdgcn_sched_barrier(0);
  }

  __syncthreads();  // protect K-buffer region before merge-buffer reuse

  // merge kv-halves by summation: grp1 exports (O, l) via LDS, grp0 combines
  if (grp == 1) {
    char* mb = lds + qh * 8704;
#pragma unroll
    for (int dc = 0; dc < 2; ++dc)
#pragma unroll
      for (int rr = 0; rr < 4; ++rr) {
        f32x4 t;
#pragma unroll
        for (int e = 0; e < 4; ++e) t[e] = oacc[dc][rr * 4 + e];
        *(f32x4*)(mb + (dc * 4 + rr) * 1024 + lane * 16) = t;
      }
    *(float*)(mb + 8192 + lane * 4) = lacc[0];
  }
  __syncthreads();
  if (grp == 0) {
    const char* mb = lds + qh * 8704;
    const float l2 = *(const float*)(mb + 8192 + lane * 4);
    const float linv = 1.0f / (lacc[0] + l2);
    bf16* orow = aout + (size_t)(b * Ss + q0 + lq) * Hh + h * DHh;
#pragma unroll
    for (int dc = 0; dc < 2; ++dc)
#pragma unroll
      for (int rr = 0; rr < 4; ++rr) {
        const f32x4 o2 = *(const f32x4*)(mb + (dc * 4 + rr) * 1024 + lane * 16);
        bf16x4 ov;
#pragma unroll
        for (int e = 0; e < 4; ++e)
          ov[e] = (bf16)((oacc[dc][rr * 4 + e] + o2[e]) * linv);
        *(bf16x4*)(orow + dc * 32 + rr * 8 + hi * 4) = ov;
      }
  }
}

extern "C" void kernel_launch(void* const* d_in, const int* in_sizes, int n_in,
                              void* d_out, int out_size, void* d_ws, size_t ws_size,
                              hipStream_t stream) {
  const float* x     = (const float*)d_in[0];
  const float* w_qkv = (const float*)d_in[1];
  const float* w_out = (const float*)d_in[2];
  const float* b_out = (const float*)d_in[3];
  char* ws = (char*)d_ws;
  bf16* xb    = (bf16*)(ws + 0);
  bf16* wqkvb = (bf16*)(ws + 6291456);
  bf16* woutb = (bf16*)(ws + 9830400);
  bf16* qkb   = (bf16*)(ws + 11010048);
  bf16* VtG   = (bf16*)(ws + 23592960);
  bf16* aoutb = (bf16*)(ws + 29884416);

  cvt_f32_bf16<<<3072, 256, 0, stream>>>(x,     xb,    Mm * Hh / 4);
  cvt_f32_bf16<<<1728, 256, 0, stream>>>(w_qkv, wqkvb, N3 * Hh / 4);
  cvt_f32_bf16<<<576,  256, 0, stream>>>(w_out, woutb, Hh * Hh / 4);

  gemm_bt<QKW, 0><<<dim3(18, 32), 256, 0, stream>>>(xb, wqkvb, qkb, VtG, nullptr, nullptr);
  attn_fwd4<<<768, 256, 0, stream>>>(qkb, VtG, aoutb);
  gemm_bt<Hh, 1><<<dim3(6, 32), 256, 0, stream>>>(aoutb, woutb, nullptr, nullptr,
                                                  (float*)d_out, b_out);
}

// Round 6
// 98.020 us; speedup vs baseline: 1.2315x; 1.2288x over previous
//
#include <hip/hip_runtime.h>
#include <cstdint>
#include <cstddef>

typedef __bf16 bf16;
typedef __bf16 bf16x8 __attribute__((ext_vector_type(8)));
typedef __bf16 bf16x4 __attribute__((ext_vector_type(4)));
typedef float  f32x4  __attribute__((ext_vector_type(4)));
typedef float  f32x16 __attribute__((ext_vector_type(16)));

constexpr int Bb  = 2;
constexpr int Ss  = 2048;
constexpr int Hh  = 768;
constexpr int NHh = 12;
constexpr int DHh = 64;
constexpr int Mm  = Bb * Ss;   // 4096
constexpr int N3  = 3 * Hh;    // 2304
constexpr int QKW = 2 * Hh;    // 1536 (Q,K packed buffer row width)

__device__ __forceinline__ float fexp2(float x) { return __builtin_amdgcn_exp2f(x); }

__device__ __forceinline__ void gload_lds16(void* lds, const void* g) {
  __builtin_amdgcn_global_load_lds(
      (__attribute__((address_space(1))) void*)(uintptr_t)g,
      (__attribute__((address_space(3))) void*)(uint32_t)(uintptr_t)lds,
      16, 0, 0);
}

__global__ void cvt_f32_bf16(const float* __restrict__ in, bf16* __restrict__ out, int n4) {
  int i = blockIdx.x * blockDim.x + threadIdx.x;
  int st = gridDim.x * blockDim.x;
  for (; i < n4; i += st) {
    float4 v = ((const float4*)in)[i];
    bf16x4 o;
    o[0] = (bf16)v.x; o[1] = (bf16)v.y; o[2] = (bf16)v.z; o[3] = (bf16)v.w;
    ((bf16x4*)out)[i] = o;
  }
}

// C = A[M,768] * Bw[N,768]^T. OUTMODE 0: bf16 out (Q,K region -> Cb stride CSTRIDE,
// V region -> Vfrag in MFMA-A-fragment order:
//   element (bh, kv, d) -> Vfrag[(((bh*128 + kv/16)*2 + d/32)*64 + ((kv>>3)&1)*32 + (d&31))*8 + (kv&7)]
// so a wave's vf[s][dc] load is 64 lanes x 16B fully coalesced.
// OUTMODE 1: f32 out + bias, stride CSTRIDE.
template<int CSTRIDE, int OUTMODE>
__global__ __launch_bounds__(256, 2)
void gemm_bt(const bf16* __restrict__ A, const bf16* __restrict__ Bw,
             bf16* __restrict__ Cb, bf16* __restrict__ VtG,
             float* __restrict__ Cf, const float* __restrict__ bias)
{
  constexpr int K = 768;
  __shared__ bf16 As[128 * 32];
  __shared__ bf16 Bs[128 * 32];
  const int tid  = threadIdx.x;
  const int wid  = tid >> 6, lane = tid & 63;
  const int lr   = lane & 15, lk = lane >> 4;
  const int n0   = blockIdx.x * 128, m0 = blockIdx.y * 128;
  const int wm   = (wid >> 1) * 64, wn = (wid & 1) * 64;

  f32x4 acc[4][4] = {};

  const char* Ag = (const char*)(A  + (size_t)m0 * K) + (size_t)(tid >> 2) * (K * 2) + (tid & 3) * 16;
  const char* Bg = (const char*)(Bw + (size_t)n0 * K) + (size_t)(tid >> 2) * (K * 2) + (tid & 3) * 16;
  char* AsW = (char*)As + wid * 1024;
  char* BsW = (char*)Bs + wid * 1024;
  constexpr size_t rstep = (size_t)64 * K * 2;

  for (int kb = 0; kb < K; kb += 32) {
    gload_lds16(AsW,        Ag + (size_t)kb * 2);
    gload_lds16(AsW + 4096, Ag + rstep + (size_t)kb * 2);
    gload_lds16(BsW,        Bg + (size_t)kb * 2);
    gload_lds16(BsW + 4096, Bg + rstep + (size_t)kb * 2);
    __syncthreads();
    bf16x8 af[4], bfv[4];
#pragma unroll
    for (int i = 0; i < 4; ++i) {
      af[i]  = *(const bf16x8*)((const char*)As + ((wm + i * 16 + lr) * 32 + lk * 8) * 2);
      bfv[i] = *(const bf16x8*)((const char*)Bs + ((wn + i * 16 + lr) * 32 + lk * 8) * 2);
    }
#pragma unroll
    for (int i = 0; i < 4; ++i)
#pragma unroll
      for (int j = 0; j < 4; ++j)
        acc[i][j] = __builtin_amdgcn_mfma_f32_16x16x32_bf16(af[i], bfv[j], acc[i][j], 0, 0, 0);
    __syncthreads();
  }

  if constexpr (OUTMODE == 1) {
#pragma unroll
    for (int i = 0; i < 4; ++i)
#pragma unroll
      for (int j = 0; j < 4; ++j) {
        const int n = n0 + wn + j * 16 + lr;
        const float bv = bias[n];
#pragma unroll
        for (int r = 0; r < 4; ++r) {
          const int m = m0 + wm + i * 16 + lk * 4 + r;
          Cf[(size_t)m * CSTRIDE + n] = acc[i][j][r] + bv;
        }
      }
  } else {
    if (n0 < QKW) {
#pragma unroll
      for (int i = 0; i < 4; ++i)
#pragma unroll
        for (int j = 0; j < 4; ++j) {
          const int n = n0 + wn + j * 16 + lr;
#pragma unroll
          for (int r = 0; r < 4; ++r) {
            const int m = m0 + wm + i * 16 + lk * 4 + r;
            Cb[(size_t)m * CSTRIDE + n] = (bf16)acc[i][j][r];
          }
        }
    } else {
      const int bidx = m0 >> 11;
      const int s0 = (m0 & 2047) + wm + lk * 4;
#pragma unroll
      for (int i = 0; i < 4; ++i)
#pragma unroll
        for (int j = 0; j < 4; ++j) {
          const int colv = (n0 - QKW) + wn + j * 16 + lr;
          const int hh = colv >> 6, dd = colv & 63;
          const int bh = bidx * NHh + hh;
          const int mb = s0 + i * 16;   // 4 consecutive kv positions (r=0..3)
          bf16x4 pv;
#pragma unroll
          for (int r = 0; r < 4; ++r) pv[r] = (bf16)acc[i][j][r];
          // fragment-major scatter: one 8B store (mb&7 in {0,4})
          const size_t idx8 = (((size_t)bh * 128 + (mb >> 4)) * 2 + (dd >> 5)) * 64
                              + ((mb >> 3) & 1) * 32 + (dd & 31);
          *(bf16x4*)(VtG + idx8 * 8 + (mb & 7)) = pv;
        }
    }
  }
}

// Flash attention v5: grid 768 blocks (XCD-swizzled head-major), 256 thr.
// 4 waves = 2 q-halves x 2 kv-halves. 32x32x16 MFMA, swapped QK^T.
// Unnormalized softmax (P = exp2(s)), l via ones-MFMA, permlane32_swap P^T.
// V loads COALESCED via fragment-major Vfrag layout (1KB/wave per instr).
// K double-buffered in LDS; counted-vmcnt schedule, 1 barrier/iter.
__global__ __launch_bounds__(256, 3)
void attn_fwd5(const bf16* __restrict__ qk, const bf16* __restrict__ Vfrag,
               bf16* __restrict__ aout)
{
  __shared__ __align__(16) char lds[32768];  // K tiles: grp*16384 + buf*8192
  const int tid  = threadIdx.x;
  const int wid  = tid >> 6, lane = tid & 63;
  const int lq   = lane & 31, hi = lane >> 5;
  const int qh   = wid & 1, grp = wid >> 1;

  // XCD swizzle (T1): 768 blocks, 8 XCDs, 96/XCD; head-major -> per-XCD
  // K/Q/V working set ~2.3MB, L2-resident.
  const int orig = blockIdx.x;
  const int swz  = (orig & 7) * 96 + (orig >> 3);
  const int qb   = swz & 31;
  const int bh   = swz >> 5;
  const int b    = bh / NHh, h = bh % NHh;
  const int q0   = qb * 64 + qh * 32;
  const int kvbase = grp * 1024;

  // Q B-fragments, pre-scaled by SCALE*log2(e) (softmax in base-2 domain)
  constexpr float Cs = 0.18033688011112042f;  // 0.125 * log2(e)
  const bf16* qrow = qk + (size_t)(b * Ss + q0 + lq) * QKW + h * DHh;
  bf16x8 qf[4];
#pragma unroll
  for (int j = 0; j < 4; ++j) {
    bf16x8 t = *(const bf16x8*)(qrow + j * 16 + hi * 8);
#pragma unroll
    for (int e = 0; e < 8; ++e) t[e] = (bf16)((float)t[e] * Cs);
    qf[j] = t;
  }

  // K staging: linear LDS dest, global source column pre-swizzled (rule #21)
  const int strow = qh * 32 + (lane >> 3);
  const int stcol = ((lane & 7) * 16) ^ (((lane >> 3) & 7) << 4);
  const char* Kg0 = (const char*)(qk + (size_t)(b * Ss) * QKW + Hh + h * DHh)
                    + (size_t)strow * (QKW * 2) + stcol;
  auto stageK = [&](int buf, int kvt) {
    char* db = lds + grp * 16384 + buf * 8192 + qh * 4096;
    const char* sg = Kg0 + (size_t)kvt * (QKW * 2);
#pragma unroll
    for (int c = 0; c < 4; ++c)
      gload_lds16(db + c * 1024, sg + (size_t)(c * 8) * (QKW * 2));
  };

  // fragment-major V: per (kvb= kv/16, dc) a 1KB contiguous wave-chunk
  const char* Vf = (const char*)Vfrag + (size_t)bh * 262144 + lane * 16;

  f32x16 oacc[2] = {};
  f32x16 lacc = {};
  bf16x8 ones;
#pragma unroll
  for (int e = 0; e < 8; ++e) ones[e] = (bf16)1.0f;

  stageK(0, kvbase);
  asm volatile("s_waitcnt vmcnt(0)" ::: "memory");
  __builtin_amdgcn_sched_barrier(0);

#pragma unroll 1
  for (int i = 0; i < 16; ++i) {
    const int cur = i & 1;

    __builtin_amdgcn_s_barrier();   // K_i (both qh halves) visible

    // V_i A-fragments, coalesced (oldest in vmcnt order)
    bf16x8 vf[4][2];
    {
      const char* vp = Vf + (size_t)(grp * 64 + i * 4) * 2048;
#pragma unroll
      for (int s = 0; s < 4; ++s)
#pragma unroll
        for (int dc = 0; dc < 2; ++dc)
          vf[s][dc] = *(const bf16x8*)(vp + (s * 2 + dc) * 1024);
    }

    // prefetch K_{i+1} (dummy wrap on last iter; drained before merge)
    stageK(cur ^ 1, kvbase + ((i + 1) & 15) * 64);
    __builtin_amdgcn_sched_barrier(0);

    // S^T = K * Q^T  (D[kv][q]; lane: q = lq, kv = (r&3)+8*(r>>2)+4*hi +32*kvc)
    f32x16 sacc[2];
    __builtin_amdgcn_s_setprio(1);
#pragma unroll
    for (int kvc = 0; kvc < 2; ++kvc) {
      f32x16 s = {};
      const int row = kvc * 32 + lq;
      const char* kb = lds + grp * 16384 + cur * 8192 + row * 128;
      const int sw = (lq & 7) << 4;
#pragma unroll
      for (int j = 0; j < 4; ++j) {
        bf16x8 kf = *(const bf16x8*)(kb + ((j * 32 + hi * 16) ^ sw));
        s = __builtin_amdgcn_mfma_f32_32x32x16_bf16(kf, qf[j], s, 0, 0, 0);
      }
      sacc[kvc] = s;
    }
    __builtin_amdgcn_s_setprio(0);

    // P = exp2(S) unnormalized; pack to bf16 pairs
    uint32_t w[2][8];
#pragma unroll
    for (int kvc = 0; kvc < 2; ++kvc)
#pragma unroll
      for (int m = 0; m < 8; ++m) {
        union { bf16 hh[2]; uint32_t u; } cv;
        cv.hh[0] = (bf16)fexp2(sacc[kvc][2 * m]);
        cv.hh[1] = (bf16)fexp2(sacc[kvc][2 * m + 1]);
        w[kvc][m] = cv.u;
      }

    // V_i retired (8 oldest); K-prefetch (4 newest) may stay in flight
    asm volatile("s_waitcnt vmcnt(4)" ::: "memory");
    __builtin_amdgcn_sched_barrier(0);

    // build P^T B-fragments via permlane32_swap and accumulate O^T, l
    __builtin_amdgcn_s_setprio(1);
#pragma unroll
    for (int s = 0; s < 4; ++s) {
      const int kvc = s >> 1, sb = s & 1;
      uint32_t a0 = w[kvc][4 * sb + 0], b0 = w[kvc][4 * sb + 2];
      uint32_t a1 = w[kvc][4 * sb + 1], b1 = w[kvc][4 * sb + 3];
      asm("v_permlane32_swap_b32 %0, %1" : "+v"(a0), "+v"(b0));
      asm("v_permlane32_swap_b32 %0, %1" : "+v"(a1), "+v"(b1));
      union { uint32_t u[4]; bf16x8 v; } pf;
      pf.u[0] = a0; pf.u[1] = a1; pf.u[2] = b0; pf.u[3] = b1;
#pragma unroll
      for (int dc = 0; dc < 2; ++dc)
        oacc[dc] = __builtin_amdgcn_mfma_f32_32x32x16_bf16(vf[s][dc], pf.v, oacc[dc], 0, 0, 0);
      lacc = __builtin_amdgcn_mfma_f32_32x32x16_bf16(ones, pf.v, lacc, 0, 0, 0);
    }
    __builtin_amdgcn_s_setprio(0);

    // my K-prefetch landed (full-iteration window); barrier at next iter top
    asm volatile("s_waitcnt vmcnt(0)" ::: "memory");
    __builtin_amdgcn_sched_barrier(0);
  }

  __syncthreads();  // protect K-buffer region before merge-buffer reuse

  // merge kv-halves by summation: grp1 exports (O, l) via LDS, grp0 combines
  if (grp == 1) {
    char* mb = lds + qh * 8704;
#pragma unroll
    for (int dc = 0; dc < 2; ++dc)
#pragma unroll
      for (int rr = 0; rr < 4; ++rr) {
        f32x4 t;
#pragma unroll
        for (int e = 0; e < 4; ++e) t[e] = oacc[dc][rr * 4 + e];
        *(f32x4*)(mb + (dc * 4 + rr) * 1024 + lane * 16) = t;
      }
    *(float*)(mb + 8192 + lane * 4) = lacc[0];
  }
  __syncthreads();
  if (grp == 0) {
    const char* mb = lds + qh * 8704;
    const float l2 = *(const float*)(mb + 8192 + lane * 4);
    const float linv = 1.0f / (lacc[0] + l2);
    bf16* orow = aout + (size_t)(b * Ss + q0 + lq) * Hh + h * DHh;
#pragma unroll
    for (int dc = 0; dc < 2; ++dc)
#pragma unroll
      for (int rr = 0; rr < 4; ++rr) {
        const f32x4 o2 = *(const f32x4*)(mb + (dc * 4 + rr) * 1024 + lane * 16);
        bf16x4 ov;
#pragma unroll
        for (int e = 0; e < 4; ++e)
          ov[e] = (bf16)((oacc[dc][rr * 4 + e] + o2[e]) * linv);
        *(bf16x4*)(orow + dc * 32 + rr * 8 + hi * 4) = ov;
      }
  }
}

extern "C" void kernel_launch(void* const* d_in, const int* in_sizes, int n_in,
                              void* d_out, int out_size, void* d_ws, size_t ws_size,
                              hipStream_t stream) {
  const float* x     = (const float*)d_in[0];
  const float* w_qkv = (const float*)d_in[1];
  const float* w_out = (const float*)d_in[2];
  const float* b_out = (const float*)d_in[3];
  char* ws = (char*)d_ws;
  bf16* xb    = (bf16*)(ws + 0);
  bf16* wqkvb = (bf16*)(ws + 6291456);
  bf16* woutb = (bf16*)(ws + 9830400);
  bf16* qkb   = (bf16*)(ws + 11010048);
  bf16* VtG   = (bf16*)(ws + 23592960);   // now fragment-major Vfrag, same size
  bf16* aoutb = (bf16*)(ws + 29884416);

  cvt_f32_bf16<<<3072, 256, 0, stream>>>(x,     xb,    Mm * Hh / 4);
  cvt_f32_bf16<<<1728, 256, 0, stream>>>(w_qkv, wqkvb, N3 * Hh / 4);
  cvt_f32_bf16<<<576,  256, 0, stream>>>(w_out, woutb, Hh * Hh / 4);

  gemm_bt<QKW, 0><<<dim3(18, 32), 256, 0, stream>>>(xb, wqkvb, qkb, VtG, nullptr, nullptr);
  attn_fwd5<<<768, 256, 0, stream>>>(qkb, VtG, aoutb);
  gemm_bt<Hh, 1><<<dim3(6, 32), 256, 0, stream>>>(aoutb, woutb, nullptr, nullptr,
                                                  (float*)d_out, b_out);
}

// Round 7
// 87.902 us; speedup vs baseline: 1.3733x; 1.1151x over previous
//
#include <hip/hip_runtime.h>
#include <cstdint>
#include <cstddef>

typedef __bf16 bf16;
typedef __bf16 bf16x8 __attribute__((ext_vector_type(8)));
typedef __bf16 bf16x4 __attribute__((ext_vector_type(4)));
typedef float  f32x4  __attribute__((ext_vector_type(4)));
typedef float  f32x16 __attribute__((ext_vector_type(16)));

constexpr int Bb  = 2;
constexpr int Ss  = 2048;
constexpr int Hh  = 768;
constexpr int NHh = 12;
constexpr int DHh = 64;
constexpr int Mm  = Bb * Ss;   // 4096
constexpr int N3  = 3 * Hh;    // 2304
constexpr int QKW = 2 * Hh;    // 1536 (Q,K packed buffer row width)

__device__ __forceinline__ float fexp2(float x) { return __builtin_amdgcn_exp2f(x); }

__device__ __forceinline__ void gload_lds16(void* lds, const void* g) {
  __builtin_amdgcn_global_load_lds(
      (__attribute__((address_space(1))) void*)(uintptr_t)g,
      (__attribute__((address_space(3))) void*)(uint32_t)(uintptr_t)lds,
      16, 0, 0);
}

// single kernel converts all three f32 inputs to bf16 (saves 2 launches)
__global__ void cvt3_f32_bf16(const float* __restrict__ x,  bf16* __restrict__ xb,
                              const float* __restrict__ w1, bf16* __restrict__ w1b,
                              const float* __restrict__ w2, bf16* __restrict__ w2b) {
  const int st = gridDim.x * blockDim.x;
  int i0 = blockIdx.x * blockDim.x + threadIdx.x;
  for (int i = i0; i < 786432; i += st) {       // x: 4096*768/4
    float4 v = ((const float4*)x)[i];
    bf16x4 o; o[0]=(bf16)v.x; o[1]=(bf16)v.y; o[2]=(bf16)v.z; o[3]=(bf16)v.w;
    ((bf16x4*)xb)[i] = o;
  }
  for (int i = i0; i < 442368; i += st) {       // w_qkv: 2304*768/4
    float4 v = ((const float4*)w1)[i];
    bf16x4 o; o[0]=(bf16)v.x; o[1]=(bf16)v.y; o[2]=(bf16)v.z; o[3]=(bf16)v.w;
    ((bf16x4*)w1b)[i] = o;
  }
  for (int i = i0; i < 147456; i += st) {       // w_out: 768*768/4
    float4 v = ((const float4*)w2)[i];
    bf16x4 o; o[0]=(bf16)v.x; o[1]=(bf16)v.y; o[2]=(bf16)v.z; o[3]=(bf16)v.w;
    ((bf16x4*)w2b)[i] = o;
  }
}

// C = A[M,768] * Bw[N,768]^T, tile BM x 128, double-buffered LDS, 1 barrier/iter.
// OUTMODE 0 (BM=128): bf16 out (Q,K region -> Cb stride CSTRIDE, V region -> Vfrag
// in MFMA-A-fragment order). OUTMODE 1: f32 out + bias, stride CSTRIDE.
template<int CSTRIDE, int OUTMODE, int BM>
__global__ __launch_bounds__(256, 2)
void gemm_bt(const bf16* __restrict__ A, const bf16* __restrict__ Bw,
             bf16* __restrict__ Cb, bf16* __restrict__ VtG,
             float* __restrict__ Cf, const float* __restrict__ bias)
{
  constexpr int K = 768;
  constexpr int NT = K / 32;          // 24 K-steps
  constexpr int MI = BM / 32;         // acc row-frags per wave
  constexpr int ABUF = BM * 64;       // bytes per A buffer
  __shared__ bf16 As[2][BM * 32];
  __shared__ bf16 Bs[2][128 * 32];
  const int tid  = threadIdx.x;
  const int wid  = tid >> 6, lane = tid & 63;
  const int lr   = lane & 15, lk = lane >> 4;
  const int n0   = blockIdx.x * 128, m0 = blockIdx.y * BM;
  const int wm   = (wid >> 1) * (BM / 2), wn = (wid & 1) * 64;

  f32x4 acc[MI][4] = {};

  const char* Ag = (const char*)(A  + (size_t)m0 * K) + (size_t)(tid >> 2) * (K * 2) + (tid & 3) * 16;
  const char* Bg = (const char*)(Bw + (size_t)n0 * K) + (size_t)(tid >> 2) * (K * 2) + (tid & 3) * 16;
  constexpr size_t rstep = (size_t)64 * K * 2;

  auto stage = [&](int buf, int kb) {
    char* aw = (char*)As + buf * ABUF + wid * 1024;
    char* bw = (char*)Bs + buf * 8192 + wid * 1024;
    gload_lds16(aw, Ag + (size_t)kb * 2);
    if constexpr (BM == 128)
      gload_lds16(aw + 4096, Ag + rstep + (size_t)kb * 2);
    gload_lds16(bw,        Bg + (size_t)kb * 2);
    gload_lds16(bw + 4096, Bg + rstep + (size_t)kb * 2);
  };

  stage(0, 0);
  asm volatile("s_waitcnt vmcnt(0)" ::: "memory");
  __syncthreads();

#pragma unroll 1
  for (int t = 0; t < NT; ++t) {
    const int cur = t & 1;
    if (t + 1 < NT) stage(cur ^ 1, (t + 1) * 32);
    __builtin_amdgcn_sched_barrier(0);

    bf16x8 af[MI], bfv[4];
#pragma unroll
    for (int i = 0; i < MI; ++i)
      af[i]  = *(const bf16x8*)((const char*)As + cur * ABUF + ((wm + i * 16 + lr) * 32 + lk * 8) * 2);
#pragma unroll
    for (int j = 0; j < 4; ++j)
      bfv[j] = *(const bf16x8*)((const char*)Bs + cur * 8192 + ((wn + j * 16 + lr) * 32 + lk * 8) * 2);
#pragma unroll
    for (int i = 0; i < MI; ++i)
#pragma unroll
      for (int j = 0; j < 4; ++j)
        acc[i][j] = __builtin_amdgcn_mfma_f32_16x16x32_bf16(af[i], bfv[j], acc[i][j], 0, 0, 0);

    __syncthreads();   // my prefetch drained (vmcnt0) + all waves done reading cur
  }

  if constexpr (OUTMODE == 1) {
#pragma unroll
    for (int i = 0; i < MI; ++i)
#pragma unroll
      for (int j = 0; j < 4; ++j) {
        const int n = n0 + wn + j * 16 + lr;
        const float bv = bias[n];
#pragma unroll
        for (int r = 0; r < 4; ++r) {
          const int m = m0 + wm + i * 16 + lk * 4 + r;
          Cf[(size_t)m * CSTRIDE + n] = acc[i][j][r] + bv;
        }
      }
  } else {
    if (n0 < QKW) {
#pragma unroll
      for (int i = 0; i < MI; ++i)
#pragma unroll
        for (int j = 0; j < 4; ++j) {
          const int n = n0 + wn + j * 16 + lr;
#pragma unroll
          for (int r = 0; r < 4; ++r) {
            const int m = m0 + wm + i * 16 + lk * 4 + r;
            Cb[(size_t)m * CSTRIDE + n] = (bf16)acc[i][j][r];
          }
        }
    } else {
      const int bidx = m0 >> 11;
      const int s0 = (m0 & 2047) + wm + lk * 4;
#pragma unroll
      for (int i = 0; i < MI; ++i)
#pragma unroll
        for (int j = 0; j < 4; ++j) {
          const int colv = (n0 - QKW) + wn + j * 16 + lr;
          const int hh = colv >> 6, dd = colv & 63;
          const int bh = bidx * NHh + hh;
          const int mb = s0 + i * 16;   // 4 consecutive kv positions (r=0..3)
          bf16x4 pv;
#pragma unroll
          for (int r = 0; r < 4; ++r) pv[r] = (bf16)acc[i][j][r];
          const size_t idx8 = (((size_t)bh * 128 + (mb >> 4)) * 2 + (dd >> 5)) * 64
                              + ((mb >> 3) & 1) * 32 + (dd & 31);
          *(bf16x4*)(VtG + idx8 * 8 + (mb & 7)) = pv;
        }
    }
  }
}

// Flash attention v5 (unchanged from round 6): grid 768 blocks (XCD-swizzled
// head-major), 256 thr. Unnormalized softmax, fragment-major coalesced V,
// K double-buffered in LDS, counted-vmcnt schedule.
__global__ __launch_bounds__(256, 3)
void attn_fwd5(const bf16* __restrict__ qk, const bf16* __restrict__ Vfrag,
               bf16* __restrict__ aout)
{
  __shared__ __align__(16) char lds[32768];
  const int tid  = threadIdx.x;
  const int wid  = tid >> 6, lane = tid & 63;
  const int lq   = lane & 31, hi = lane >> 5;
  const int qh   = wid & 1, grp = wid >> 1;

  const int orig = blockIdx.x;
  const int swz  = (orig & 7) * 96 + (orig >> 3);
  const int qb   = swz & 31;
  const int bh   = swz >> 5;
  const int b    = bh / NHh, h = bh % NHh;
  const int q0   = qb * 64 + qh * 32;
  const int kvbase = grp * 1024;

  constexpr float Cs = 0.18033688011112042f;  // 0.125 * log2(e)
  const bf16* qrow = qk + (size_t)(b * Ss + q0 + lq) * QKW + h * DHh;
  bf16x8 qf[4];
#pragma unroll
  for (int j = 0; j < 4; ++j) {
    bf16x8 t = *(const bf16x8*)(qrow + j * 16 + hi * 8);
#pragma unroll
    for (int e = 0; e < 8; ++e) t[e] = (bf16)((float)t[e] * Cs);
    qf[j] = t;
  }

  const int strow = qh * 32 + (lane >> 3);
  const int stcol = ((lane & 7) * 16) ^ (((lane >> 3) & 7) << 4);
  const char* Kg0 = (const char*)(qk + (size_t)(b * Ss) * QKW + Hh + h * DHh)
                    + (size_t)strow * (QKW * 2) + stcol;
  auto stageK = [&](int buf, int kvt) {
    char* db = lds + grp * 16384 + buf * 8192 + qh * 4096;
    const char* sg = Kg0 + (size_t)kvt * (QKW * 2);
#pragma unroll
    for (int c = 0; c < 4; ++c)
      gload_lds16(db + c * 1024, sg + (size_t)(c * 8) * (QKW * 2));
  };

  const char* Vf = (const char*)Vfrag + (size_t)bh * 262144 + lane * 16;

  f32x16 oacc[2] = {};
  f32x16 lacc = {};
  bf16x8 ones;
#pragma unroll
  for (int e = 0; e < 8; ++e) ones[e] = (bf16)1.0f;

  stageK(0, kvbase);
  asm volatile("s_waitcnt vmcnt(0)" ::: "memory");
  __builtin_amdgcn_sched_barrier(0);

#pragma unroll 1
  for (int i = 0; i < 16; ++i) {
    const int cur = i & 1;

    __builtin_amdgcn_s_barrier();

    bf16x8 vf[4][2];
    {
      const char* vp = Vf + (size_t)(grp * 64 + i * 4) * 2048;
#pragma unroll
      for (int s = 0; s < 4; ++s)
#pragma unroll
        for (int dc = 0; dc < 2; ++dc)
          vf[s][dc] = *(const bf16x8*)(vp + (s * 2 + dc) * 1024);
    }

    stageK(cur ^ 1, kvbase + ((i + 1) & 15) * 64);
    __builtin_amdgcn_sched_barrier(0);

    f32x16 sacc[2];
    __builtin_amdgcn_s_setprio(1);
#pragma unroll
    for (int kvc = 0; kvc < 2; ++kvc) {
      f32x16 s = {};
      const int row = kvc * 32 + lq;
      const char* kb = lds + grp * 16384 + cur * 8192 + row * 128;
      const int sw = (lq & 7) << 4;
#pragma unroll
      for (int j = 0; j < 4; ++j) {
        bf16x8 kf = *(const bf16x8*)(kb + ((j * 32 + hi * 16) ^ sw));
        s = __builtin_amdgcn_mfma_f32_32x32x16_bf16(kf, qf[j], s, 0, 0, 0);
      }
      sacc[kvc] = s;
    }
    __builtin_amdgcn_s_setprio(0);

    uint32_t w[2][8];
#pragma unroll
    for (int kvc = 0; kvc < 2; ++kvc)
#pragma unroll
      for (int m = 0; m < 8; ++m) {
        union { bf16 hh[2]; uint32_t u; } cv;
        cv.hh[0] = (bf16)fexp2(sacc[kvc][2 * m]);
        cv.hh[1] = (bf16)fexp2(sacc[kvc][2 * m + 1]);
        w[kvc][m] = cv.u;
      }

    asm volatile("s_waitcnt vmcnt(4)" ::: "memory");
    __builtin_amdgcn_sched_barrier(0);

    __builtin_amdgcn_s_setprio(1);
#pragma unroll
    for (int s = 0; s < 4; ++s) {
      const int kvc = s >> 1, sb = s & 1;
      uint32_t a0 = w[kvc][4 * sb + 0], b0 = w[kvc][4 * sb + 2];
      uint32_t a1 = w[kvc][4 * sb + 1], b1 = w[kvc][4 * sb + 3];
      asm("v_permlane32_swap_b32 %0, %1" : "+v"(a0), "+v"(b0));
      asm("v_permlane32_swap_b32 %0, %1" : "+v"(a1), "+v"(b1));
      union { uint32_t u[4]; bf16x8 v; } pf;
      pf.u[0] = a0; pf.u[1] = a1; pf.u[2] = b0; pf.u[3] = b1;
#pragma unroll
      for (int dc = 0; dc < 2; ++dc)
        oacc[dc] = __builtin_amdgcn_mfma_f32_32x32x16_bf16(vf[s][dc], pf.v, oacc[dc], 0, 0, 0);
      lacc = __builtin_amdgcn_mfma_f32_32x32x16_bf16(ones, pf.v, lacc, 0, 0, 0);
    }
    __builtin_amdgcn_s_setprio(0);

    asm volatile("s_waitcnt vmcnt(0)" ::: "memory");
    __builtin_amdgcn_sched_barrier(0);
  }

  __syncthreads();

  if (grp == 1) {
    char* mb = lds + qh * 8704;
#pragma unroll
    for (int dc = 0; dc < 2; ++dc)
#pragma unroll
      for (int rr = 0; rr < 4; ++rr) {
        f32x4 t;
#pragma unroll
        for (int e = 0; e < 4; ++e) t[e] = oacc[dc][rr * 4 + e];
        *(f32x4*)(mb + (dc * 4 + rr) * 1024 + lane * 16) = t;
      }
    *(float*)(mb + 8192 + lane * 4) = lacc[0];
  }
  __syncthreads();
  if (grp == 0) {
    const char* mb = lds + qh * 8704;
    const float l2 = *(const float*)(mb + 8192 + lane * 4);
    const float linv = 1.0f / (lacc[0] + l2);
    bf16* orow = aout + (size_t)(b * Ss + q0 + lq) * Hh + h * DHh;
#pragma unroll
    for (int dc = 0; dc < 2; ++dc)
#pragma unroll
      for (int rr = 0; rr < 4; ++rr) {
        const f32x4 o2 = *(const f32x4*)(mb + (dc * 4 + rr) * 1024 + lane * 16);
        bf16x4 ov;
#pragma unroll
        for (int e = 0; e < 4; ++e)
          ov[e] = (bf16)((oacc[dc][rr * 4 + e] + o2[e]) * linv);
        *(bf16x4*)(orow + dc * 32 + rr * 8 + hi * 4) = ov;
      }
  }
}

extern "C" void kernel_launch(void* const* d_in, const int* in_sizes, int n_in,
                              void* d_out, int out_size, void* d_ws, size_t ws_size,
                              hipStream_t stream) {
  const float* x     = (const float*)d_in[0];
  const float* w_qkv = (const float*)d_in[1];
  const float* w_out = (const float*)d_in[2];
  const float* b_out = (const float*)d_in[3];
  char* ws = (char*)d_ws;
  bf16* xb    = (bf16*)(ws + 0);
  bf16* wqkvb = (bf16*)(ws + 6291456);
  bf16* woutb = (bf16*)(ws + 9830400);
  bf16* qkb   = (bf16*)(ws + 11010048);
  bf16* Vfrag = (bf16*)(ws + 23592960);
  bf16* aoutb = (bf16*)(ws + 29884416);

  cvt3_f32_bf16<<<2048, 256, 0, stream>>>(x, xb, w_qkv, wqkvb, w_out, woutb);

  gemm_bt<QKW, 0, 128><<<dim3(18, 32), 256, 0, stream>>>(xb, wqkvb, qkb, Vfrag, nullptr, nullptr);
  attn_fwd5<<<768, 256, 0, stream>>>(qkb, Vfrag, aoutb);
  gemm_bt<Hh, 1, 64><<<dim3(6, 64), 256, 0, stream>>>(aoutb, woutb, nullptr, nullptr,
                                                      (float*)d_out, b_out);
}